// Round 9
// baseline (46.913 us; speedup 1.0000x reference)
//
#include <hip/hip_runtime.h>

typedef __bf16 bf16x8 __attribute__((ext_vector_type(8)));
typedef __bf16 bf16x4 __attribute__((ext_vector_type(4)));
typedef float  f32x4  __attribute__((ext_vector_type(4)));

#define D100 100
#define NROWS (4096*64)            // 262144 rows of X
#define NTILES (NROWS/16)          // 16384 16-row tiles
#define NCT 7                      // col tiles: 7*16 = 112 >= 100
#define NKS 4                      // k steps: 4*32 = 128 (k=112 = bias row)
#define FRAG_ELEMS (NCT*NKS*64*8)  // 14336 bf16 fragment elements (28672 B)
#define NBLK (NTILES/8)            // 2048 blocks; 8 waves, ONE tile per wave

typedef const __attribute__((address_space(1))) void gvoid;
typedef __attribute__((address_space(3))) void lvoid;

// ---------------------------------------------------------------------------
// Kernel 1: build M = W^T * S in MFMA fragment order (bf16, zero-padded),
// with the bias row folded in at k==112: M[112][n] = (b*S)[n].
// M[k][n] = sum_d W[d*100+k] * S[d*100+n].
// Fragment order: wsM[((ct*4+ks)*64 + lane)*8 + j] holds
//   M[ ks*32 + (lane>>4)*8 + j ][ ct*16 + (lane&15) ]
// ---------------------------------------------------------------------------
__global__ __launch_bounds__(256) void prep_kernel(
    const float* __restrict__ W, const float* __restrict__ bvec,
    const float* __restrict__ S, __bf16* __restrict__ wsM) {
  int tid = blockIdx.x * 256 + threadIdx.x;
  if (tid >= FRAG_ELEMS) return;
  int j    = tid & 7;
  int lane = (tid >> 3) & 63;
  int ks   = (tid >> 9) & 3;
  int ct   = tid >> 11;
  int k = ks * 32 + ((lane >> 4) * 8) + j;
  int n = ct * 16 + (lane & 15);
  float acc = 0.f;
  if (n < D100) {
    if (k < D100) {
      float a0 = 0.f, a1 = 0.f, a2 = 0.f, a3 = 0.f;
      for (int d = 0; d < D100; d += 4) {
        a0 += W[(d + 0) * D100 + k] * S[(d + 0) * D100 + n];
        a1 += W[(d + 1) * D100 + k] * S[(d + 1) * D100 + n];
        a2 += W[(d + 2) * D100 + k] * S[(d + 2) * D100 + n];
        a3 += W[(d + 3) * D100 + k] * S[(d + 3) * D100 + n];
      }
      acc = (a0 + a1) + (a2 + a3);
    } else if (k == 112) {  // bias row
      for (int d = 0; d < D100; ++d) acc += bvec[d] * S[d * D100 + n];
    }
  }
  wsM[tid] = (__bf16)acc;
}

// ---------------------------------------------------------------------------
// Kernel 2: out[r][n] = sum_k x[r][k] * M[k][n]   (bias via M[112], xf=1)
// 2048 blocks x 8 waves; ONE tile per wave; wave ends in a tight store
// burst and exits (clean-merge invariant, r3/r7: WRITE ~= output bytes).
// x path: linear per-lane f32x4 loads (full 128B lines) -> reg cvt to bf16
// -> linear ds_write_b64 into a wave-private 3200B row-major bf16 buffer
// -> fragment ds_read_b64 pairs (4-phase, conflict-free at 200B stride).
// bf16 staging halves ldsX: total LDS 54272B <= 54613 -> 3 blocks/CU
// (24 waves/CU, 75%) for better load/compute/store anti-phasing.
// Output: DIRECT scattered f32x4 burst from acc (r7-measured clean).
// ---------------------------------------------------------------------------
__global__ __launch_bounds__(512, 6) void gemm_kernel(
    const float* __restrict__ x, const __bf16* __restrict__ wsM,
    float* __restrict__ out) {
  __shared__ __align__(16) __bf16 ldsB[FRAG_ELEMS];  // 28672 B
  __shared__ __align__(16) __bf16 ldsX[8 * 1600];    // 25600 B (3200 B/wave)

  const int t    = threadIdx.x;
  const int lane = t & 63;
  const int l16  = lane & 15;
  const int lg   = lane >> 4;
  const int w    = t >> 6;
  const int tile = blockIdx.x * 8 + w;

  // ---- x tile: linear per-lane loads, issued first (HBM latency) ----
  const char* xsrc = (const char*)x + (size_t)tile * 6400 + (size_t)lane * 16;
  f32x4 xv[7];
#pragma unroll
  for (int c = 0; c < 6; ++c) xv[c] = *(const f32x4*)(xsrc + c * 1024);
  if (lane < 16) xv[6] = *(const f32x4*)(xsrc + 6144);

  // ---- M fragments -> LDS, linear (28 x 1KB chunks split across waves) ----
  {
    const char* bsrc = (const char*)wsM + (size_t)lane * 16;
    for (int c = w; c < 28; c += 8)
      __builtin_amdgcn_global_load_lds((gvoid*)(bsrc + c * 1024),
                                       (lvoid*)((char*)ldsB + c * 1024),
                                       16, 0, 0);
  }

  // ---- convert to bf16 and stage linearly into wave-private ldsx ----
  __bf16* ldsx = ldsX + w * 1600;  // 16 rows x 100 bf16, row stride 200 B
#pragma unroll
  for (int c = 0; c < 6; ++c) {
    bf16x4 h;
#pragma unroll
    for (int j = 0; j < 4; ++j) h[j] = (__bf16)xv[c][j];
    *(bf16x4*)(ldsx + c * 256 + lane * 4) = h;  // elem = float index
  }
  if (lane < 16) {
    bf16x4 h;
#pragma unroll
    for (int j = 0; j < 4; ++j) h[j] = (__bf16)xv[6][j];
    *(bf16x4*)(ldsx + 1536 + lane * 4) = h;
  }
  __syncthreads();  // ldsB + ldsx ready (drains vmcnt + lgkmcnt)

  f32x4 acc[NCT];
#pragma unroll
  for (int ct = 0; ct < NCT; ++ct) acc[ct] = (f32x4){0.f, 0.f, 0.f, 0.f};

  const bf16x8* Bv  = (const bf16x8*)ldsB;
  const __bf16* xrow = ldsx + l16 * D100;

#pragma unroll
  for (int ks = 0; ks < NKS; ++ks) {
    bf16x8 xf;
    if (ks < 3) {
      bf16x4 lo = *(const bf16x4*)(xrow + ks * 32 + lg * 8);
      bf16x4 hi = *(const bf16x4*)(xrow + ks * 32 + lg * 8 + 4);
#pragma unroll
      for (int j = 0; j < 4; ++j) {
        xf[j]     = lo[j];
        xf[j + 4] = hi[j];
      }
    } else {
      // k = 96 + lg*8 + j: lg==0 -> x[96..99]; lg==2,j==0 (k=112) -> 1.0
      bf16x4 lo = *(const bf16x4*)(xrow + 96);  // bytes 192..199, in-row
#pragma unroll
      for (int j = 0; j < 4; ++j) {
        xf[j]     = (lg == 0) ? lo[j] : (__bf16)0.f;
        xf[j + 4] = (__bf16)0.f;
      }
      if (lg == 2) xf[0] = (__bf16)1.0f;
    }
#pragma unroll
    for (int ct = 0; ct < NCT; ++ct)
      acc[ct] = __builtin_amdgcn_mfma_f32_16x16x32_bf16(
          Bv[(ct * NKS + ks) * 64 + lane], xf, acc[ct], 0, 0, 0);
  }

  // ---- tight direct store burst (lane owns out[l16][ct*16+lg*4..+3]) ----
  float* orow = out + (size_t)tile * (16 * D100) + l16 * D100 + lg * 4;
#pragma unroll
  for (int ct = 0; ct < NCT; ++ct) {
    if (ct < 6 || lg == 0)  // cols 100..111 don't exist
      *(f32x4*)(orow + ct * 16) = acc[ct];
  }
}

extern "C" void kernel_launch(void* const* d_in, const int* in_sizes, int n_in,
                              void* d_out, int out_size, void* d_ws,
                              size_t ws_size, hipStream_t stream) {
  const float* x = (const float*)d_in[0];
  const float* W = (const float*)d_in[1];
  const float* b = (const float*)d_in[2];
  const float* S = (const float*)d_in[3];
  __bf16* wsM = (__bf16*)d_ws;
  float*  out = (float*)d_out;

  hipLaunchKernelGGL(prep_kernel, dim3(56), dim3(256), 0, stream,
                     W, b, S, wsM);
  hipLaunchKernelGGL(gemm_kernel, dim3(NBLK), dim3(512), 0, stream,
                     x, wsM, out);
}